// Round 13
// baseline (264.146 us; speedup 1.0000x reference)
//
#include <hip/hip_runtime.h>
#include <hip/hip_bf16.h>

typedef __attribute__((ext_vector_type(8))) __bf16 bf16x8;
typedef __attribute__((ext_vector_type(4))) short short4v;
typedef __attribute__((ext_vector_type(4))) float f32x4;
typedef __attribute__((ext_vector_type(4))) unsigned int uint4v;
typedef __attribute__((ext_vector_type(2))) unsigned int uint2v;

#define S_LEN 2048
#define DIM_  1024
#define HDIM  64
// SCALE * log2(e), folded into Q at projection time
#define SCALE2 0.045084441f

#define EXP2F(x) __builtin_amdgcn_exp2f(x)

// 16B-granularity XOR swizzle for [R][64] bf16 LDS tiles (rows = 128 B).
#define ATTN_SWZ(row, col8) (((row) * 64) + (((col8) ^ ((row) & 7)) << 3))

__device__ __forceinline__ void async_copy16(const void* gp, void* lp) {
  __builtin_amdgcn_global_load_lds(
      (const __attribute__((address_space(1))) unsigned int*)gp,
      (__attribute__((address_space(3))) unsigned int*)lp, 16, 0, 0);
}

__device__ __forceinline__ unsigned f2bf_u(float f) {
  unsigned u = __builtin_bit_cast(unsigned, f);
  return (u + 0x7FFFu + ((u >> 16) & 1u)) >> 16;
}
__device__ __forceinline__ unsigned pack2(float a, float b) {
  return f2bf_u(a) | (f2bf_u(b) << 16);
}
// single-instruction packed f32x2 -> bf16x2 (v_cvt_pk_bf16_f32), a in low half
__device__ __forceinline__ unsigned cvtpk(float a, float b) {
  float2 f; f.x = a; f.y = b;
  __hip_bfloat162 h = __float22bfloat162_rn(f);
  unsigned u;
  __builtin_memcpy(&u, &h, 4);
  return u;
}

// ---------------- input f32 -> bf16 conversion + mask ballot (fused) ----------------
__global__ __launch_bounds__(256) void cvt_kernel(
    const float* __restrict__ s0, const float* __restrict__ s1, const float* __restrict__ s2,
    const float* __restrict__ s3, const float* __restrict__ s4, const float* __restrict__ s5,
    const float* __restrict__ s6,
    __hip_bfloat16* __restrict__ d0, __hip_bfloat16* __restrict__ d1, __hip_bfloat16* __restrict__ d2,
    __hip_bfloat16* __restrict__ d3, __hip_bfloat16* __restrict__ d4, __hip_bfloat16* __restrict__ d5,
    __hip_bfloat16* __restrict__ d6,
    const int* __restrict__ mask, unsigned long long* __restrict__ bits)
{
  if (blockIdx.y == 7) {
    // mask int32 -> 64-bit words via ballot; 16 words per wave
    int wave = threadIdx.x >> 6, lane = threadIdx.x & 63;
    int gw = blockIdx.x * 4 + wave;           // 0..8191
#pragma unroll
    for (int it = 0; it < 16; ++it) {
      int w = gw * 16 + it;                   // 0..131071
      int m = mask[(size_t)w * 64 + lane];
      unsigned long long bal = __ballot(m != 0);
      if (lane == 0) bits[w] = bal;
    }
    return;
  }
  const float* srcs[7] = {s0, s1, s2, s3, s4, s5, s6};
  __hip_bfloat16* dsts[7] = {d0, d1, d2, d3, d4, d5, d6};
  const int sizes[7] = {4194304, 4194304, 4194304, 1048576, 1048576, 1048576, 1048576};
  int rg = blockIdx.y;
  int base = (blockIdx.x * 256 + threadIdx.x) * 8;
  if (base >= sizes[rg]) return;
  const float* s = srcs[rg] + base;
  f32x4 a = *(const f32x4*)s;
  f32x4 b = *(const f32x4*)(s + 4);
  uint4v o;
  o.x = pack2(a[0], a[1]); o.y = pack2(a[2], a[3]);
  o.z = pack2(b[0], b[1]); o.w = pack2(b[2], b[3]);
  *(uint4v*)(dsts[rg] + base) = o;
}

// XCD-aware L2 swizzle: blocks sharing one W-panel (same n0) co-locate on one XCD.
// bid%8 = XCD (round-robin dispatch); 4 (n-tile, m-band) combos per XCD.
__device__ __forceinline__ void swz(int r, int& m0, int& n0) {
  int c  = ((r & 7) << 2) | (r >> 6);  // combo 0..31
  int xl = (r >> 3) & 7;
  m0 = ((c >> 3) * 8 + xl) * 128;
  n0 = (c & 7) * 128;
}

// ---------------- QKV projection (bf16, double-buffered async staging) ----------------
// Epilogue: LDS-transpose (reusing the 32 KB staging buffer) + coalesced
// 16B stores for Q/K and VT.
__global__ __launch_bounds__(256) void qkv_gemm_kernel(
    const __hip_bfloat16* __restrict__ xq, const __hip_bfloat16* __restrict__ xk,
    const __hip_bfloat16* __restrict__ xv,
    const __hip_bfloat16* __restrict__ Wq, const float* __restrict__ bq,
    const __hip_bfloat16* __restrict__ Wk, const float* __restrict__ bk,
    const __hip_bfloat16* __restrict__ Wv, const float* __restrict__ bv,
    __hip_bfloat16* __restrict__ Q, __hip_bfloat16* __restrict__ Kk,
    __hip_bfloat16* __restrict__ VT)
{
  const __hip_bfloat16 *X, *W; const float* bias;
  if (blockIdx.z == 0)      { X = xq; W = Wq; bias = bq; }
  else if (blockIdx.z == 1) { X = xk; W = Wk; bias = bk; }
  else                      { X = xv; W = Wv; bias = bv; }

  constexpr int K = 1024, N = 1024;
  __shared__ alignas(16) __hip_bfloat16 SM[4][128 * 32];
  const int tid  = threadIdx.x;
  const int lane = tid & 63;
  const int wave = tid >> 6;
  const int t    = lane & 15;
  const int quad = lane >> 4;
  const int wm   = wave >> 1;
  const int wn   = wave & 1;
  int m0, n0;
  swz(blockIdx.x, m0, n0);

  f32x4 acc[4][4] = {};

  const int c0 = tid, c1 = 256 + tid;
  const int r0 = c0 >> 2, o0 = (c0 & 3) * 8;
  const int r1 = c1 >> 2, o1 = (c1 & 3) * 8;
  const __hip_bfloat16* xp0 = &X[(size_t)(m0 + r0) * K + o0];
  const __hip_bfloat16* xp1 = &X[(size_t)(m0 + r1) * K + o1];
  const __hip_bfloat16* wp0 = &W[(size_t)(n0 + r0) * K + o0];
  const __hip_bfloat16* wp1 = &W[(size_t)(n0 + r1) * K + o1];

  async_copy16(xp0, &SM[0][c0 * 8]);
  async_copy16(xp1, &SM[0][c1 * 8]);
  async_copy16(wp0, &SM[2][c0 * 8]);
  async_copy16(wp1, &SM[2][c1 * 8]);

  int buf = 0;
  for (int k0 = 0; k0 < K; k0 += 32) {
    __syncthreads();
    if (k0 + 32 < K) {
      int nb = buf ^ 1;
      int kn = k0 + 32;
      async_copy16(xp0 + kn, &SM[nb][c0 * 8]);
      async_copy16(xp1 + kn, &SM[nb][c1 * 8]);
      async_copy16(wp0 + kn, &SM[2 + nb][c0 * 8]);
      async_copy16(wp1 + kn, &SM[2 + nb][c1 * 8]);
    }
    bf16x8 a[4], b[4];
#pragma unroll
    for (int i = 0; i < 4; ++i)
      a[i] = *(const bf16x8*)&SM[buf][(wm * 64 + i * 16 + t) * 32 + quad * 8];
#pragma unroll
    for (int j = 0; j < 4; ++j)
      b[j] = *(const bf16x8*)&SM[2 + buf][(wn * 64 + j * 16 + t) * 32 + quad * 8];
#pragma unroll
    for (int i = 0; i < 4; ++i)
#pragma unroll
      for (int j = 0; j < 4; ++j)
        acc[i][j] = __builtin_amdgcn_mfma_f32_16x16x32_bf16(a[i], b[j], acc[i][j], 0, 0, 0);
    buf ^= 1;
  }

  float bj[4];
#pragma unroll
  for (int j = 0; j < 4; ++j)
    bj[j] = bias[n0 + wn * 64 + j * 16 + t];

  __syncthreads();
  __hip_bfloat16* SMf = &SM[0][0];

  if (blockIdx.z == 2) {
#pragma unroll
    for (int i = 0; i < 4; ++i) {
      int mlb = wm * 8 + i * 2 + (quad >> 1);
#pragma unroll
      for (int j = 0; j < 4; ++j) {
        int nl = wn * 64 + j * 16 + t;
        int blk = (mlb & 8) | ((mlb & 7) ^ (nl & 7));
        uint2v pk;
        pk.x = pack2(acc[i][j][0] + bj[j], acc[i][j][1] + bj[j]);
        pk.y = pack2(acc[i][j][2] + bj[j], acc[i][j][3] + bj[j]);
        *(uint2v*)&SMf[nl * 128 + blk * 8 + (quad & 1) * 4] = pk;
      }
    }
    __syncthreads();
    const int bb = m0 >> 11, kv0 = m0 & 2047;
#pragma unroll
    for (int pass = 0; pass < 8; ++pass) {
      int nl = pass * 16 + (tid >> 4);
      int lb = tid & 15;
      int blk = (lb & 8) | ((lb & 7) ^ (nl & 7));
      uint4 x = *(const uint4*)&SMf[nl * 128 + blk * 8];
      *(uint4*)&VT[(size_t)(bb * 1024 + n0 + nl) * 2048 + kv0 + lb * 8] = x;
    }
  } else {
    const bool isq = (blockIdx.z == 0);
    __hip_bfloat16* Out = isq ? Q : Kk;
    const float sc = isq ? SCALE2 : 1.0f;
#pragma unroll
    for (int i = 0; i < 4; ++i)
#pragma unroll
      for (int j = 0; j < 4; ++j) {
        int nlb = wn * 8 + j * 2 + (t >> 3);
        int nin = t & 7;
#pragma unroll
        for (int r = 0; r < 4; ++r) {
          int ml = wm * 64 + i * 16 + quad * 4 + r;
          int blk = (nlb & 8) | ((nlb & 7) ^ (ml & 7));
          SMf[ml * 128 + blk * 8 + nin] =
              __float2bfloat16((acc[i][j][r] + bj[j]) * sc);
        }
      }
    __syncthreads();
#pragma unroll
    for (int pass = 0; pass < 8; ++pass) {
      int ml = pass * 16 + (tid >> 4);
      int lb = tid & 15;
      int blk = (lb & 8) | ((lb & 7) ^ (ml & 7));
      uint4 x = *(const uint4*)&SMf[ml * 128 + blk * 8];
      *(uint4*)&Out[(size_t)(m0 + ml) * N + n0 + lb * 8] = x;
    }
  }
}

// ---------------- Output projection ----------------
// R18: 64x128 tiles -> 512 blocks = 2 blocks/CU (was 256 = 1/CU; a lone
// 4-wave block can't hide its own barrier drains). Each wave: 64 rows x
// 32 cols, acc[4][2], 8 MFMA/K-step. LDS 24 KB.
__global__ __launch_bounds__(256) void proj_gemm_kernel(
    const __hip_bfloat16* __restrict__ X, const __hip_bfloat16* __restrict__ W,
    const float* __restrict__ bias, float* __restrict__ Out)
{
  constexpr int K = 1024, N = 1024;
  __shared__ alignas(16) __hip_bfloat16 As[2][64 * 32];
  __shared__ alignas(16) __hip_bfloat16 Bs[2][128 * 32];
  const int tid  = threadIdx.x;
  const int lane = tid & 63;
  const int wave = tid >> 6;   // = wn (0..3): 32-col slice
  const int t    = lane & 15;
  const int quad = lane >> 4;
  // XCD swizzle: bid%8 = XCD; each XCD owns an 8-m-tile band, sweeps all n
  const int r  = blockIdx.x;           // 0..511
  const int m0 = ((r & 7) * 8 + ((r >> 3) & 7)) * 64;
  const int n0 = (r >> 6) * 128;

  f32x4 acc[4][2] = {};

  // staging: A = 1 chunk/thread (64x32), B = 2 chunks/thread (128x32)
  const int ra = tid >> 2, oa = (tid & 3) * 8;
  const int c0 = tid, c1 = 256 + tid;
  const int rb0 = c0 >> 2, ob0 = (c0 & 3) * 8;
  const int rb1 = c1 >> 2, ob1 = (c1 & 3) * 8;
  const __hip_bfloat16* xp  = &X[(size_t)(m0 + ra) * K + oa];
  const __hip_bfloat16* wp0 = &W[(size_t)(n0 + rb0) * K + ob0];
  const __hip_bfloat16* wp1 = &W[(size_t)(n0 + rb1) * K + ob1];

  async_copy16(xp,  &As[0][tid * 8]);
  async_copy16(wp0, &Bs[0][c0 * 8]);
  async_copy16(wp1, &Bs[0][c1 * 8]);

  int buf = 0;
  for (int k0 = 0; k0 < K; k0 += 32) {
    __syncthreads();
    if (k0 + 32 < K) {
      int nb = buf ^ 1;
      int kn = k0 + 32;
      async_copy16(xp + kn,  &As[nb][tid * 8]);
      async_copy16(wp0 + kn, &Bs[nb][c0 * 8]);
      async_copy16(wp1 + kn, &Bs[nb][c1 * 8]);
    }
    bf16x8 a[4], b[2];
#pragma unroll
    for (int i = 0; i < 4; ++i)
      a[i] = *(const bf16x8*)&As[buf][(i * 16 + t) * 32 + quad * 8];
#pragma unroll
    for (int j = 0; j < 2; ++j)
      b[j] = *(const bf16x8*)&Bs[buf][(wave * 32 + j * 16 + t) * 32 + quad * 8];
#pragma unroll
    for (int i = 0; i < 4; ++i)
#pragma unroll
      for (int j = 0; j < 2; ++j)
        acc[i][j] = __builtin_amdgcn_mfma_f32_16x16x32_bf16(a[i], b[j], acc[i][j], 0, 0, 0);
    buf ^= 1;
  }

  float bj[2];
#pragma unroll
  for (int j = 0; j < 2; ++j)
    bj[j] = bias[n0 + wave * 32 + j * 16 + t];
#pragma unroll
  for (int i = 0; i < 4; ++i)
#pragma unroll
    for (int j = 0; j < 2; ++j)
#pragma unroll
      for (int rr = 0; rr < 4; ++rr) {
        int m = m0 + i * 16 + quad * 4 + rr;
        int n = n0 + wave * 32 + j * 16 + t;
        Out[(size_t)m * N + n] = acc[i][j][rr] + bj[j];
      }
}

// ---------------- Flash attention (R11/R14 structure — measured 69.5-70.1 us) ----------------
// QBLK=64, 2-buffer global_load_lds staging (pre-swizzled source), 2x-unrolled
// kv loop with compile-time buf, hoisted LDS offsets, setprio around compute.
// Mask select BEFORE exp2 (R16's exp2-first reorder measured -10us regression).
__global__ __launch_bounds__(256) void attn_kernel(
    const __hip_bfloat16* __restrict__ Qb,
    const __hip_bfloat16* __restrict__ Kb,
    const __hip_bfloat16* __restrict__ VT,
    const unsigned long long* __restrict__ mbits,
    __hip_bfloat16* __restrict__ Ob)
{
  const int bid = blockIdx.x;
  // XCD-aware remap: bid%8 = XCD; groups g = (bid&7)*4 + (bid>>8); qt = (bid>>3)&31
  const int qt = (bid >> 3) & 31;
  const int g  = ((bid & 7) << 2) | (bid >> 8);
  const int h  = g & 15;
  const int b  = g >> 4;
  const int qb = qt * 64;

  __shared__ alignas(16) __hip_bfloat16 Qs[64 * 64];
  __shared__ alignas(16) __hip_bfloat16 Ks[2][64 * 64];
  __shared__ alignas(16) __hip_bfloat16 Vt[2][64 * 64];   // Vt[dv][kv]

  const int tid  = threadIdx.x;
  const int lane = tid & 63;
  const int wave = tid >> 6;
  const int t    = lane & 15;
  const int quad = lane >> 4;

  // staging geometry: chunk c in {tid, 256+tid}: row = c>>3, blk = c&7.
  // LDS dest is linear (c*16 bytes). Global source column is pre-swizzled
  // (col8 = blk ^ (row&7)) so LDS content matches ATTN_SWZ reads.
  const int r0 = tid >> 3;
  const int r1 = 32 + r0;
  const int k0c = ((tid & 7) ^ (r0 & 7)) << 3;
  const int k1c = ((tid & 7) ^ (r1 & 7)) << 3;
  const __hip_bfloat16* kp0 = &Kb[((size_t)(b * S_LEN + r0)) * DIM_ + h * HDIM + k0c];
  const __hip_bfloat16* kp1 = &Kb[((size_t)(b * S_LEN + r1)) * DIM_ + h * HDIM + k1c];
  const size_t vtbase = (size_t)((b * 16 + h) * 64) * 2048;
  const __hip_bfloat16* vp0 = &VT[vtbase + (size_t)r0 * 2048 + k0c];
  const __hip_bfloat16* vp1 = &VT[vtbase + (size_t)r1 * 2048 + k1c];

  // prologue: async-stage K/V tile 0 into buf 0
  async_copy16(kp0, &Ks[0][tid * 8]);
  async_copy16(kp1, &Ks[0][(256 + tid) * 8]);
  async_copy16(vp0, &Vt[0][tid * 8]);
  async_copy16(vp1, &Vt[0][(256 + tid) * 8]);

  // stage Q (swizzled, sync)
#pragma unroll
  for (int r = 0; r < 2; ++r) {
    int c = r * 256 + tid;
    int row = c >> 3, c8 = c & 7;
    uint4 raw = *(const uint4*)&Qb[((size_t)(b * S_LEN + qb + row)) * DIM_ + h * HDIM + c8 * 8];
    *(uint4*)&Qs[ATTN_SWZ(row, c8)] = raw;
  }
  __syncthreads();   // Q ready, tile0 staging drained (vmcnt0 before barrier)

  bf16x8 qf[2];
#pragma unroll
  for (int ks = 0; ks < 2; ++ks)
    qf[ks] = *(const bf16x8*)&Qs[ATTN_SWZ(wave * 16 + t, ks * 4 + quad)];

  // hoisted loop-invariant LDS element offsets (compile-time indexed)
  int koff[8];
#pragma unroll
  for (int i = 0; i < 4; ++i) {
    koff[i]     = ATTN_SWZ(i * 16 + t, quad);
    koff[4 + i] = ATTN_SWZ(i * 16 + t, 4 + quad);
  }
  int voff[16];
#pragma unroll
  for (int j = 0; j < 4; ++j)
#pragma unroll
    for (int n = 0; n < 4; ++n)
      voff[j * 4 + n] = (n * 16 + t) * 64 +
          (((j * 2 + (quad >> 1)) ^ (t & 7)) << 3) + (quad & 1) * 4;

  f32x4 lp4 = {0.f, 0.f, 0.f, 0.f};  // 4 independent denominator chains
  f32x4 o[4] = {};                   // O^T[dv = n*16+quad*4+r][q = t]

  const int qg = qb + wave * 16 + t;
  const size_t mbase = ((size_t)b * S_LEN + qg) * 32;
  const int qshift = quad * 4;

// one kv-tile body; BUF is a compile-time constant (0/1)
#define ATTN_TILE(kvt, BUF)                                                   \
  {                                                                           \
    unsigned long long mw = mbits[mbase + (kvt)];                             \
    if ((kvt) > 0) __syncthreads(); /* drains staging of BUF */               \
    if ((kvt) + 1 < 32) {                                                     \
      size_t koffg = (size_t)((kvt) + 1) * 64 * DIM_;                         \
      int    voffg = ((kvt) + 1) * 64;                                        \
      async_copy16(kp0 + koffg, &Ks[(BUF) ^ 1][tid * 8]);                     \
      async_copy16(kp1 + koffg, &Ks[(BUF) ^ 1][(256 + tid) * 8]);             \
      async_copy16(vp0 + voffg, &Vt[(BUF) ^ 1][tid * 8]);                     \
      async_copy16(vp1 + voffg, &Vt[(BUF) ^ 1][(256 + tid) * 8]);             \
    }                                                                         \
    __builtin_amdgcn_s_setprio(1);                                            \
    unsigned long long mwq = mw >> qshift;                                    \
    unsigned mlo = (unsigned)mwq, mhi = (unsigned)(mwq >> 32);                \
    unsigned mqv[4] = {mlo & 0xFu, (mlo >> 16) & 0xFu,                        \
                       mhi & 0xFu, (mhi >> 16) & 0xFu};                       \
    float e[4][4];                                                            \
    _Pragma("unroll")                                                         \
    for (int i = 0; i < 4; ++i) {                                             \
      f32x4 z = {};                                                           \
      bf16x8 a0 = *(const bf16x8*)&Ks[BUF][koff[i]];                          \
      z = __builtin_amdgcn_mfma_f32_16x16x32_bf16(a0, qf[0], z, 0, 0, 0);     \
      bf16x8 a1 = *(const bf16x8*)&Ks[BUF][koff[4 + i]];                      \
      z = __builtin_amdgcn_mfma_f32_16x16x32_bf16(a1, qf[1], z, 0, 0, 0);     \
      _Pragma("unroll")                                                       \
      for (int r = 0; r < 4; ++r) {                                           \
        float v = ((mqv[i] >> r) & 1u) ? -1e20f : z[r];                       \
        float ex = EXP2F(v);                                                  \
        e[i][r] = ex;                                                         \
        lp4[r] += ex;                                                         \
      }                                                                       \
    }                                                                         \
    short4v pf[4];                                                            \
    _Pragma("unroll")                                                         \
    for (int j = 0; j < 4; ++j) {                                             \
      uint2v pk;                                                              \
      pk.x = cvtpk(e[j][0], e[j][1]);                                         \
      pk.y = cvtpk(e[j][2], e[j][3]);                                         \
      pf[j] = __builtin_bit_cast(short4v, pk);                                \
    }                                                                         \
    _Pragma("unroll")                                                         \
    for (int j = 0; j < 4; ++j)                                               \
      _Pragma("unroll")                                                       \
      for (int n = 0; n < 4; ++n) {                                           \
        short4v va = *(const short4v*)&Vt[BUF][voff[j * 4 + n]];              \
        o[n] = __builtin_amdgcn_mfma_f32_16x16x16bf16_1k(va, pf[j], o[n],     \
                                                         0, 0, 0);            \
      }                                                                       \
    __builtin_amdgcn_s_setprio(0);                                            \
  }

  ATTN_TILE(0, 0)
  for (int kvt = 1; kvt < 31; kvt += 2) {
    ATTN_TILE(kvt, 1)
    ATTN_TILE(kvt + 1, 0)
  }
  ATTN_TILE(31, 1)
#undef ATTN_TILE

  // reduce denominator across quads (kv split), normalize
  float lp = (lp4[0] + lp4[1]) + (lp4[2] + lp4[3]);
  lp += __shfl_xor(lp, 16, 64);
  lp += __shfl_xor(lp, 32, 64);
  float rl = 1.0f / lp;

  // transpose O^T -> O via Qs (swizzled), coalesced store
  __hip_bfloat16* Ts = Qs;
  __syncthreads();
#pragma unroll
  for (int n = 0; n < 4; ++n) {
    uint2v pk;
    pk.x = cvtpk(o[n][0] * rl, o[n][1] * rl);
    pk.y = cvtpk(o[n][2] * rl, o[n][3] * rl);
    *(uint2v*)&Ts[(wave * 16 + t) * 64 +
                  (((n * 2 + (quad >> 1)) ^ (t & 7)) << 3) + (quad & 1) * 4] = pk;
  }
  __syncthreads();
  {
    int row = tid >> 2;          // q local
    int b0  = (tid & 3) * 2;     // 16B block base
    uint4 x0 = *(const uint4*)&Ts[row * 64 + ((b0 ^ (row & 7)) << 3)];
    uint4 x1 = *(const uint4*)&Ts[row * 64 + (((b0 + 1) ^ (row & 7)) << 3)];
    int d0 = (tid & 3) * 16;
    __hip_bfloat16* dst = &Ob[((size_t)(b * S_LEN + qb + row)) * DIM_ + h * HDIM + d0];
    *(uint4*)dst = x0;
    *(uint4*)(dst + 8) = x1;
  }
}

extern "C" void kernel_launch(void* const* d_in, const int* in_sizes, int n_in,
                              void* d_out, int out_size, void* d_ws, size_t ws_size,
                              hipStream_t stream) {
  const float* q  = (const float*)d_in[0];
  const float* k  = (const float*)d_in[1];
  const float* v  = (const float*)d_in[2];
  const int*   mk = (const int*)d_in[3];
  const float* Wq = (const float*)d_in[4];
  const float* bq = (const float*)d_in[5];
  const float* Wk = (const float*)d_in[6];
  const float* bk = (const float*)d_in[7];
  const float* Wv = (const float*)d_in[8];
  const float* bv = (const float*)d_in[9];
  const float* Wo = (const float*)d_in[10];
  const float* bo = (const float*)d_in[11];
  float* out = (float*)d_out;

  char* ws = (char*)d_ws;
  const size_t MB = 1024 * 1024;
  __hip_bfloat16* Qb  = (__hip_bfloat16*)(ws);
  __hip_bfloat16* Kb  = (__hip_bfloat16*)(ws + 8  * MB);
  __hip_bfloat16* VTb = (__hip_bfloat16*)(ws + 16 * MB);
  __hip_bfloat16* Ob  = (__hip_bfloat16*)(ws + 24 * MB);
  __hip_bfloat16* xqb = (__hip_bfloat16*)(ws + 32 * MB);
  __hip_bfloat16* xkb = (__hip_bfloat16*)(ws + 40 * MB);
  __hip_bfloat16* xvb = (__hip_bfloat16*)(ws + 48 * MB);
  __hip_bfloat16* Wqb = (__hip_bfloat16*)(ws + 56 * MB);
  __hip_bfloat16* Wkb = (__hip_bfloat16*)(ws + 58 * MB);
  __hip_bfloat16* Wvb = (__hip_bfloat16*)(ws + 60 * MB);
  __hip_bfloat16* Wob = (__hip_bfloat16*)(ws + 62 * MB);
  unsigned long long* mbits = (unsigned long long*)(ws + 64 * MB);

  cvt_kernel<<<dim3(2048, 8), 256, 0, stream>>>(q, k, v, Wq, Wk, Wv, Wo,
                                                xqb, xkb, xvb, Wqb, Wkb, Wvb, Wob,
                                                mk, mbits);
  qkv_gemm_kernel<<<dim3(256, 1, 3), 256, 0, stream>>>(xqb, xkb, xvb,
                                                       Wqb, bq, Wkb, bk, Wvb, bv,
                                                       Qb, Kb, VTb);
  attn_kernel<<<dim3(1024), 256, 0, stream>>>(Qb, Kb, VTb, mbits, Ob);
  proj_gemm_kernel<<<dim3(512), 256, 0, stream>>>(Ob, Wob, bo, out);
}

// Round 14
// 256.434 us; speedup vs baseline: 1.0301x; 1.0301x over previous
//
#include <hip/hip_runtime.h>
#include <hip/hip_bf16.h>

typedef __attribute__((ext_vector_type(8))) __bf16 bf16x8;
typedef __attribute__((ext_vector_type(4))) short short4v;
typedef __attribute__((ext_vector_type(4))) float f32x4;
typedef __attribute__((ext_vector_type(4))) unsigned int uint4v;
typedef __attribute__((ext_vector_type(2))) unsigned int uint2v;

#define S_LEN 2048
#define DIM_  1024
#define HDIM  64
// SCALE * log2(e), folded into Q at projection time
#define SCALE2 0.045084441f

#define EXP2F(x) __builtin_amdgcn_exp2f(x)

// 16B-granularity XOR swizzle for [R][64] bf16 LDS tiles (rows = 128 B).
#define ATTN_SWZ(row, col8) (((row) * 64) + (((col8) ^ ((row) & 7)) << 3))

__device__ __forceinline__ void async_copy16(const void* gp, void* lp) {
  __builtin_amdgcn_global_load_lds(
      (const __attribute__((address_space(1))) unsigned int*)gp,
      (__attribute__((address_space(3))) unsigned int*)lp, 16, 0, 0);
}

__device__ __forceinline__ unsigned f2bf_u(float f) {
  unsigned u = __builtin_bit_cast(unsigned, f);
  return (u + 0x7FFFu + ((u >> 16) & 1u)) >> 16;
}
__device__ __forceinline__ unsigned pack2(float a, float b) {
  return f2bf_u(a) | (f2bf_u(b) << 16);
}
// single-instruction packed f32x2 -> bf16x2 (v_cvt_pk_bf16_f32), a in low half
__device__ __forceinline__ unsigned cvtpk(float a, float b) {
  float2 f; f.x = a; f.y = b;
  __hip_bfloat162 h = __float22bfloat162_rn(f);
  unsigned u;
  __builtin_memcpy(&u, &h, 4);
  return u;
}

// ---------------- input f32 -> bf16 conversion + mask ballot (fused) ----------------
__global__ __launch_bounds__(256) void cvt_kernel(
    const float* __restrict__ s0, const float* __restrict__ s1, const float* __restrict__ s2,
    const float* __restrict__ s3, const float* __restrict__ s4, const float* __restrict__ s5,
    const float* __restrict__ s6,
    __hip_bfloat16* __restrict__ d0, __hip_bfloat16* __restrict__ d1, __hip_bfloat16* __restrict__ d2,
    __hip_bfloat16* __restrict__ d3, __hip_bfloat16* __restrict__ d4, __hip_bfloat16* __restrict__ d5,
    __hip_bfloat16* __restrict__ d6,
    const int* __restrict__ mask, unsigned long long* __restrict__ bits)
{
  if (blockIdx.y == 7) {
    // mask int32 -> 64-bit words via ballot; 16 words per wave
    int wave = threadIdx.x >> 6, lane = threadIdx.x & 63;
    int gw = blockIdx.x * 4 + wave;           // 0..8191
#pragma unroll
    for (int it = 0; it < 16; ++it) {
      int w = gw * 16 + it;                   // 0..131071
      int m = mask[(size_t)w * 64 + lane];
      unsigned long long bal = __ballot(m != 0);
      if (lane == 0) bits[w] = bal;
    }
    return;
  }
  const float* srcs[7] = {s0, s1, s2, s3, s4, s5, s6};
  __hip_bfloat16* dsts[7] = {d0, d1, d2, d3, d4, d5, d6};
  const int sizes[7] = {4194304, 4194304, 4194304, 1048576, 1048576, 1048576, 1048576};
  int rg = blockIdx.y;
  int base = (blockIdx.x * 256 + threadIdx.x) * 8;
  if (base >= sizes[rg]) return;
  const float* s = srcs[rg] + base;
  f32x4 a = *(const f32x4*)s;
  f32x4 b = *(const f32x4*)(s + 4);
  uint4v o;
  o.x = pack2(a[0], a[1]); o.y = pack2(a[2], a[3]);
  o.z = pack2(b[0], b[1]); o.w = pack2(b[2], b[3]);
  *(uint4v*)(dsts[rg] + base) = o;
}

// XCD-aware L2 swizzle: blocks sharing one W-panel (same n0) co-locate on one XCD.
// bid%8 = XCD (round-robin dispatch); 4 (n-tile, m-band) combos per XCD.
__device__ __forceinline__ void swz(int r, int& m0, int& n0) {
  int c  = ((r & 7) << 2) | (r >> 6);  // combo 0..31
  int xl = (r >> 3) & 7;
  m0 = ((c >> 3) * 8 + xl) * 128;
  n0 = (c & 7) * 128;
}

// ---------------- QKV projection (bf16, double-buffered async staging) ----------------
// Epilogue: LDS-transpose (reusing the 32 KB staging buffer) + coalesced
// 16B stores for Q/K and VT.
__global__ __launch_bounds__(256) void qkv_gemm_kernel(
    const __hip_bfloat16* __restrict__ xq, const __hip_bfloat16* __restrict__ xk,
    const __hip_bfloat16* __restrict__ xv,
    const __hip_bfloat16* __restrict__ Wq, const float* __restrict__ bq,
    const __hip_bfloat16* __restrict__ Wk, const float* __restrict__ bk,
    const __hip_bfloat16* __restrict__ Wv, const float* __restrict__ bv,
    __hip_bfloat16* __restrict__ Q, __hip_bfloat16* __restrict__ Kk,
    __hip_bfloat16* __restrict__ VT)
{
  const __hip_bfloat16 *X, *W; const float* bias;
  if (blockIdx.z == 0)      { X = xq; W = Wq; bias = bq; }
  else if (blockIdx.z == 1) { X = xk; W = Wk; bias = bk; }
  else                      { X = xv; W = Wv; bias = bv; }

  constexpr int K = 1024, N = 1024;
  __shared__ alignas(16) __hip_bfloat16 SM[4][128 * 32];
  const int tid  = threadIdx.x;
  const int lane = tid & 63;
  const int wave = tid >> 6;
  const int t    = lane & 15;
  const int quad = lane >> 4;
  const int wm   = wave >> 1;
  const int wn   = wave & 1;
  int m0, n0;
  swz(blockIdx.x, m0, n0);

  f32x4 acc[4][4] = {};

  const int c0 = tid, c1 = 256 + tid;
  const int r0 = c0 >> 2, o0 = (c0 & 3) * 8;
  const int r1 = c1 >> 2, o1 = (c1 & 3) * 8;
  const __hip_bfloat16* xp0 = &X[(size_t)(m0 + r0) * K + o0];
  const __hip_bfloat16* xp1 = &X[(size_t)(m0 + r1) * K + o1];
  const __hip_bfloat16* wp0 = &W[(size_t)(n0 + r0) * K + o0];
  const __hip_bfloat16* wp1 = &W[(size_t)(n0 + r1) * K + o1];

  async_copy16(xp0, &SM[0][c0 * 8]);
  async_copy16(xp1, &SM[0][c1 * 8]);
  async_copy16(wp0, &SM[2][c0 * 8]);
  async_copy16(wp1, &SM[2][c1 * 8]);

  int buf = 0;
  for (int k0 = 0; k0 < K; k0 += 32) {
    __syncthreads();
    if (k0 + 32 < K) {
      int nb = buf ^ 1;
      int kn = k0 + 32;
      async_copy16(xp0 + kn, &SM[nb][c0 * 8]);
      async_copy16(xp1 + kn, &SM[nb][c1 * 8]);
      async_copy16(wp0 + kn, &SM[2 + nb][c0 * 8]);
      async_copy16(wp1 + kn, &SM[2 + nb][c1 * 8]);
    }
    bf16x8 a[4], b[4];
#pragma unroll
    for (int i = 0; i < 4; ++i)
      a[i] = *(const bf16x8*)&SM[buf][(wm * 64 + i * 16 + t) * 32 + quad * 8];
#pragma unroll
    for (int j = 0; j < 4; ++j)
      b[j] = *(const bf16x8*)&SM[2 + buf][(wn * 64 + j * 16 + t) * 32 + quad * 8];
#pragma unroll
    for (int i = 0; i < 4; ++i)
#pragma unroll
      for (int j = 0; j < 4; ++j)
        acc[i][j] = __builtin_amdgcn_mfma_f32_16x16x32_bf16(a[i], b[j], acc[i][j], 0, 0, 0);
    buf ^= 1;
  }

  float bj[4];
#pragma unroll
  for (int j = 0; j < 4; ++j)
    bj[j] = bias[n0 + wn * 64 + j * 16 + t];

  __syncthreads();
  __hip_bfloat16* SMf = &SM[0][0];

  if (blockIdx.z == 2) {
#pragma unroll
    for (int i = 0; i < 4; ++i) {
      int mlb = wm * 8 + i * 2 + (quad >> 1);
#pragma unroll
      for (int j = 0; j < 4; ++j) {
        int nl = wn * 64 + j * 16 + t;
        int blk = (mlb & 8) | ((mlb & 7) ^ (nl & 7));
        uint2v pk;
        pk.x = pack2(acc[i][j][0] + bj[j], acc[i][j][1] + bj[j]);
        pk.y = pack2(acc[i][j][2] + bj[j], acc[i][j][3] + bj[j]);
        *(uint2v*)&SMf[nl * 128 + blk * 8 + (quad & 1) * 4] = pk;
      }
    }
    __syncthreads();
    const int bb = m0 >> 11, kv0 = m0 & 2047;
#pragma unroll
    for (int pass = 0; pass < 8; ++pass) {
      int nl = pass * 16 + (tid >> 4);
      int lb = tid & 15;
      int blk = (lb & 8) | ((lb & 7) ^ (nl & 7));
      uint4 x = *(const uint4*)&SMf[nl * 128 + blk * 8];
      *(uint4*)&VT[(size_t)(bb * 1024 + n0 + nl) * 2048 + kv0 + lb * 8] = x;
    }
  } else {
    const bool isq = (blockIdx.z == 0);
    __hip_bfloat16* Out = isq ? Q : Kk;
    const float sc = isq ? SCALE2 : 1.0f;
#pragma unroll
    for (int i = 0; i < 4; ++i)
#pragma unroll
      for (int j = 0; j < 4; ++j) {
        int nlb = wn * 8 + j * 2 + (t >> 3);
        int nin = t & 7;
#pragma unroll
        for (int r = 0; r < 4; ++r) {
          int ml = wm * 64 + i * 16 + quad * 4 + r;
          int blk = (nlb & 8) | ((nlb & 7) ^ (ml & 7));
          SMf[ml * 128 + blk * 8 + nin] =
              __float2bfloat16((acc[i][j][r] + bj[j]) * sc);
        }
      }
    __syncthreads();
#pragma unroll
    for (int pass = 0; pass < 8; ++pass) {
      int ml = pass * 16 + (tid >> 4);
      int lb = tid & 15;
      int blk = (lb & 8) | ((lb & 7) ^ (ml & 7));
      uint4 x = *(const uint4*)&SMf[ml * 128 + blk * 8];
      *(uint4*)&Out[(size_t)(m0 + ml) * N + n0 + lb * 8] = x;
    }
  }
}

// ---------------- Output projection (double-buffered, 128x128 tiles) ----------------
__global__ __launch_bounds__(256) void proj_gemm_kernel(
    const __hip_bfloat16* __restrict__ X, const __hip_bfloat16* __restrict__ W,
    const float* __restrict__ bias, float* __restrict__ Out)
{
  constexpr int K = 1024, N = 1024;
  __shared__ alignas(16) __hip_bfloat16 As[2][128 * 32];
  __shared__ alignas(16) __hip_bfloat16 Bs[2][128 * 32];
  const int tid  = threadIdx.x;
  const int lane = tid & 63;
  const int wave = tid >> 6;
  const int t    = lane & 15;
  const int quad = lane >> 4;
  const int wm   = wave >> 1;
  const int wn   = wave & 1;
  int m0, n0;
  swz(blockIdx.x, m0, n0);

  f32x4 acc[4][4] = {};

  const int c0 = tid, c1 = 256 + tid;
  const int r0 = c0 >> 2, o0 = (c0 & 3) * 8;
  const int r1 = c1 >> 2, o1 = (c1 & 3) * 8;
  const __hip_bfloat16* xp0 = &X[(size_t)(m0 + r0) * K + o0];
  const __hip_bfloat16* xp1 = &X[(size_t)(m0 + r1) * K + o1];
  const __hip_bfloat16* wp0 = &W[(size_t)(n0 + r0) * K + o0];
  const __hip_bfloat16* wp1 = &W[(size_t)(n0 + r1) * K + o1];

  async_copy16(xp0, &As[0][c0 * 8]);
  async_copy16(xp1, &As[0][c1 * 8]);
  async_copy16(wp0, &Bs[0][c0 * 8]);
  async_copy16(wp1, &Bs[0][c1 * 8]);

  int buf = 0;
  for (int k0 = 0; k0 < K; k0 += 32) {
    __syncthreads();
    if (k0 + 32 < K) {
      int nb = buf ^ 1;
      int kn = k0 + 32;
      async_copy16(xp0 + kn, &As[nb][c0 * 8]);
      async_copy16(xp1 + kn, &As[nb][c1 * 8]);
      async_copy16(wp0 + kn, &Bs[nb][c0 * 8]);
      async_copy16(wp1 + kn, &Bs[nb][c1 * 8]);
    }
    bf16x8 a[4], b[4];
#pragma unroll
    for (int i = 0; i < 4; ++i)
      a[i] = *(const bf16x8*)&As[buf][(wm * 64 + i * 16 + t) * 32 + quad * 8];
#pragma unroll
    for (int j = 0; j < 4; ++j)
      b[j] = *(const bf16x8*)&Bs[buf][(wn * 64 + j * 16 + t) * 32 + quad * 8];
#pragma unroll
    for (int i = 0; i < 4; ++i)
#pragma unroll
      for (int j = 0; j < 4; ++j)
        acc[i][j] = __builtin_amdgcn_mfma_f32_16x16x32_bf16(a[i], b[j], acc[i][j], 0, 0, 0);
    buf ^= 1;
  }

  float bj[4];
#pragma unroll
  for (int j = 0; j < 4; ++j)
    bj[j] = bias[n0 + wn * 64 + j * 16 + t];
#pragma unroll
  for (int i = 0; i < 4; ++i)
#pragma unroll
    for (int j = 0; j < 4; ++j)
#pragma unroll
      for (int r = 0; r < 4; ++r) {
        int m = m0 + wm * 64 + i * 16 + quad * 4 + r;
        int n = n0 + wn * 64 + j * 16 + t;
        Out[(size_t)m * N + n] = acc[i][j][r] + bj[j];
      }
}

// ---------------- Flash attention (R11/R14 structure — measured 69.3-70.4 us) ----------------
// QBLK=64, 2-buffer global_load_lds staging (pre-swizzled source), 2x-unrolled
// kv loop with compile-time buf, hoisted LDS offsets, setprio around compute.
// Mask select BEFORE exp2 (R16's exp2-first reorder measured -10us regression).
__global__ __launch_bounds__(256) void attn_kernel(
    const __hip_bfloat16* __restrict__ Qb,
    const __hip_bfloat16* __restrict__ Kb,
    const __hip_bfloat16* __restrict__ VT,
    const unsigned long long* __restrict__ mbits,
    __hip_bfloat16* __restrict__ Ob)
{
  const int bid = blockIdx.x;
  // XCD-aware remap: bid%8 = XCD; groups g = (bid&7)*4 + (bid>>8); qt = (bid>>3)&31
  const int qt = (bid >> 3) & 31;
  const int g  = ((bid & 7) << 2) | (bid >> 8);
  const int h  = g & 15;
  const int b  = g >> 4;
  const int qb = qt * 64;

  __shared__ alignas(16) __hip_bfloat16 Qs[64 * 64];
  __shared__ alignas(16) __hip_bfloat16 Ks[2][64 * 64];
  __shared__ alignas(16) __hip_bfloat16 Vt[2][64 * 64];   // Vt[dv][kv]

  const int tid  = threadIdx.x;
  const int lane = tid & 63;
  const int wave = tid >> 6;
  const int t    = lane & 15;
  const int quad = lane >> 4;

  // staging geometry: chunk c in {tid, 256+tid}: row = c>>3, blk = c&7.
  // LDS dest is linear (c*16 bytes). Global source column is pre-swizzled
  // (col8 = blk ^ (row&7)) so LDS content matches ATTN_SWZ reads.
  const int r0 = tid >> 3;
  const int r1 = 32 + r0;
  const int k0c = ((tid & 7) ^ (r0 & 7)) << 3;
  const int k1c = ((tid & 7) ^ (r1 & 7)) << 3;
  const __hip_bfloat16* kp0 = &Kb[((size_t)(b * S_LEN + r0)) * DIM_ + h * HDIM + k0c];
  const __hip_bfloat16* kp1 = &Kb[((size_t)(b * S_LEN + r1)) * DIM_ + h * HDIM + k1c];
  const size_t vtbase = (size_t)((b * 16 + h) * 64) * 2048;
  const __hip_bfloat16* vp0 = &VT[vtbase + (size_t)r0 * 2048 + k0c];
  const __hip_bfloat16* vp1 = &VT[vtbase + (size_t)r1 * 2048 + k1c];

  // prologue: async-stage K/V tile 0 into buf 0
  async_copy16(kp0, &Ks[0][tid * 8]);
  async_copy16(kp1, &Ks[0][(256 + tid) * 8]);
  async_copy16(vp0, &Vt[0][tid * 8]);
  async_copy16(vp1, &Vt[0][(256 + tid) * 8]);

  // stage Q (swizzled, sync)
#pragma unroll
  for (int r = 0; r < 2; ++r) {
    int c = r * 256 + tid;
    int row = c >> 3, c8 = c & 7;
    uint4 raw = *(const uint4*)&Qb[((size_t)(b * S_LEN + qb + row)) * DIM_ + h * HDIM + c8 * 8];
    *(uint4*)&Qs[ATTN_SWZ(row, c8)] = raw;
  }
  __syncthreads();   // Q ready, tile0 staging drained (vmcnt0 before barrier)

  bf16x8 qf[2];
#pragma unroll
  for (int ks = 0; ks < 2; ++ks)
    qf[ks] = *(const bf16x8*)&Qs[ATTN_SWZ(wave * 16 + t, ks * 4 + quad)];

  // hoisted loop-invariant LDS element offsets (compile-time indexed)
  int koff[8];
#pragma unroll
  for (int i = 0; i < 4; ++i) {
    koff[i]     = ATTN_SWZ(i * 16 + t, quad);
    koff[4 + i] = ATTN_SWZ(i * 16 + t, 4 + quad);
  }
  int voff[16];
#pragma unroll
  for (int j = 0; j < 4; ++j)
#pragma unroll
    for (int n = 0; n < 4; ++n)
      voff[j * 4 + n] = (n * 16 + t) * 64 +
          (((j * 2 + (quad >> 1)) ^ (t & 7)) << 3) + (quad & 1) * 4;

  f32x4 lp4 = {0.f, 0.f, 0.f, 0.f};  // 4 independent denominator chains
  f32x4 o[4] = {};                   // O^T[dv = n*16+quad*4+r][q = t]

  const int qg = qb + wave * 16 + t;
  const size_t mbase = ((size_t)b * S_LEN + qg) * 32;
  const int qshift = quad * 4;

// one kv-tile body; BUF is a compile-time constant (0/1)
#define ATTN_TILE(kvt, BUF)                                                   \
  {                                                                           \
    unsigned long long mw = mbits[mbase + (kvt)];                             \
    if ((kvt) > 0) __syncthreads(); /* drains staging of BUF */               \
    if ((kvt) + 1 < 32) {                                                     \
      size_t koffg = (size_t)((kvt) + 1) * 64 * DIM_;                         \
      int    voffg = ((kvt) + 1) * 64;                                        \
      async_copy16(kp0 + koffg, &Ks[(BUF) ^ 1][tid * 8]);                     \
      async_copy16(kp1 + koffg, &Ks[(BUF) ^ 1][(256 + tid) * 8]);             \
      async_copy16(vp0 + voffg, &Vt[(BUF) ^ 1][tid * 8]);                     \
      async_copy16(vp1 + voffg, &Vt[(BUF) ^ 1][(256 + tid) * 8]);             \
    }                                                                         \
    __builtin_amdgcn_s_setprio(1);                                            \
    unsigned long long mwq = mw >> qshift;                                    \
    unsigned mlo = (unsigned)mwq, mhi = (unsigned)(mwq >> 32);                \
    unsigned mqv[4] = {mlo & 0xFu, (mlo >> 16) & 0xFu,                        \
                       mhi & 0xFu, (mhi >> 16) & 0xFu};                       \
    float e[4][4];                                                            \
    _Pragma("unroll")                                                         \
    for (int i = 0; i < 4; ++i) {                                             \
      f32x4 z = {};                                                           \
      bf16x8 a0 = *(const bf16x8*)&Ks[BUF][koff[i]];                          \
      z = __builtin_amdgcn_mfma_f32_16x16x32_bf16(a0, qf[0], z, 0, 0, 0);     \
      bf16x8 a1 = *(const bf16x8*)&Ks[BUF][koff[4 + i]];                      \
      z = __builtin_amdgcn_mfma_f32_16x16x32_bf16(a1, qf[1], z, 0, 0, 0);     \
      _Pragma("unroll")                                                       \
      for (int r = 0; r < 4; ++r) {                                           \
        float v = ((mqv[i] >> r) & 1u) ? -1e20f : z[r];                       \
        float ex = EXP2F(v);                                                  \
        e[i][r] = ex;                                                         \
        lp4[r] += ex;                                                         \
      }                                                                       \
    }                                                                         \
    short4v pf[4];                                                            \
    _Pragma("unroll")                                                         \
    for (int j = 0; j < 4; ++j) {                                             \
      uint2v pk;                                                              \
      pk.x = cvtpk(e[j][0], e[j][1]);                                         \
      pk.y = cvtpk(e[j][2], e[j][3]);                                         \
      pf[j] = __builtin_bit_cast(short4v, pk);                                \
    }                                                                         \
    _Pragma("unroll")                                                         \
    for (int j = 0; j < 4; ++j)                                               \
      _Pragma("unroll")                                                       \
      for (int n = 0; n < 4; ++n) {                                           \
        short4v va = *(const short4v*)&Vt[BUF][voff[j * 4 + n]];              \
        o[n] = __builtin_amdgcn_mfma_f32_16x16x16bf16_1k(va, pf[j], o[n],     \
                                                         0, 0, 0);            \
      }                                                                       \
    __builtin_amdgcn_s_setprio(0);                                            \
  }

  ATTN_TILE(0, 0)
  for (int kvt = 1; kvt < 31; kvt += 2) {
    ATTN_TILE(kvt, 1)
    ATTN_TILE(kvt + 1, 0)
  }
  ATTN_TILE(31, 1)
#undef ATTN_TILE

  // reduce denominator across quads (kv split), normalize
  float lp = (lp4[0] + lp4[1]) + (lp4[2] + lp4[3]);
  lp += __shfl_xor(lp, 16, 64);
  lp += __shfl_xor(lp, 32, 64);
  float rl = 1.0f / lp;

  // transpose O^T -> O via Qs (swizzled), coalesced store
  __hip_bfloat16* Ts = Qs;
  __syncthreads();
#pragma unroll
  for (int n = 0; n < 4; ++n) {
    uint2v pk;
    pk.x = cvtpk(o[n][0] * rl, o[n][1] * rl);
    pk.y = cvtpk(o[n][2] * rl, o[n][3] * rl);
    *(uint2v*)&Ts[(wave * 16 + t) * 64 +
                  (((n * 2 + (quad >> 1)) ^ (t & 7)) << 3) + (quad & 1) * 4] = pk;
  }
  __syncthreads();
  {
    int row = tid >> 2;          // q local
    int b0  = (tid & 3) * 2;     // 16B block base
    uint4 x0 = *(const uint4*)&Ts[row * 64 + ((b0 ^ (row & 7)) << 3)];
    uint4 x1 = *(const uint4*)&Ts[row * 64 + (((b0 + 1) ^ (row & 7)) << 3)];
    int d0 = (tid & 3) * 16;
    __hip_bfloat16* dst = &Ob[((size_t)(b * S_LEN + qb + row)) * DIM_ + h * HDIM + d0];
    *(uint4*)dst = x0;
    *(uint4*)(dst + 8) = x1;
  }
}

extern "C" void kernel_launch(void* const* d_in, const int* in_sizes, int n_in,
                              void* d_out, int out_size, void* d_ws, size_t ws_size,
                              hipStream_t stream) {
  const float* q  = (const float*)d_in[0];
  const float* k  = (const float*)d_in[1];
  const float* v  = (const float*)d_in[2];
  const int*   mk = (const int*)d_in[3];
  const float* Wq = (const float*)d_in[4];
  const float* bq = (const float*)d_in[5];
  const float* Wk = (const float*)d_in[6];
  const float* bk = (const float*)d_in[7];
  const float* Wv = (const float*)d_in[8];
  const float* bv = (const float*)d_in[9];
  const float* Wo = (const float*)d_in[10];
  const float* bo = (const float*)d_in[11];
  float* out = (float*)d_out;

  char* ws = (char*)d_ws;
  const size_t MB = 1024 * 1024;
  __hip_bfloat16* Qb  = (__hip_bfloat16*)(ws);
  __hip_bfloat16* Kb  = (__hip_bfloat16*)(ws + 8  * MB);
  __hip_bfloat16* VTb = (__hip_bfloat16*)(ws + 16 * MB);
  __hip_bfloat16* Ob  = (__hip_bfloat16*)(ws + 24 * MB);
  __hip_bfloat16* xqb = (__hip_bfloat16*)(ws + 32 * MB);
  __hip_bfloat16* xkb = (__hip_bfloat16*)(ws + 40 * MB);
  __hip_bfloat16* xvb = (__hip_bfloat16*)(ws + 48 * MB);
  __hip_bfloat16* Wqb = (__hip_bfloat16*)(ws + 56 * MB);
  __hip_bfloat16* Wkb = (__hip_bfloat16*)(ws + 58 * MB);
  __hip_bfloat16* Wvb = (__hip_bfloat16*)(ws + 60 * MB);
  __hip_bfloat16* Wob = (__hip_bfloat16*)(ws + 62 * MB);
  unsigned long long* mbits = (unsigned long long*)(ws + 64 * MB);

  cvt_kernel<<<dim3(2048, 8), 256, 0, stream>>>(q, k, v, Wq, Wk, Wv, Wo,
                                                xqb, xkb, xvb, Wqb, Wkb, Wvb, Wob,
                                                mk, mbits);
  qkv_gemm_kernel<<<dim3(256, 1, 3), 256, 0, stream>>>(xqb, xkb, xvb,
                                                       Wqb, bq, Wkb, bk, Wvb, bv,
                                                       Qb, Kb, VTb);
  attn_kernel<<<dim3(1024), 256, 0, stream>>>(Qb, Kb, VTb, mbits, Ob);
  proj_gemm_kernel<<<dim3(256), 256, 0, stream>>>(Ob, Wob, bo, out);
}